// Round 2
// baseline (555.402 us; speedup 1.0000x reference)
//
#include <hip/hip_runtime.h>
#include <math.h>

// Problem constants (fixed by the reference).
#define KCODES 512
#define DDIM   64
#define NROWS  262144
#define ND     ((size_t)NROWS * DDIM)
#define MBLK   128           // rows per block (R7: 2x, B-frag reuse)
#define CAP    6             // candidate-list capacity per row
// sigma-scale margin: sigma = dot - c^2/2 = -s/2. Required s-margin 1.14e-4
// (R5 analysis: 2*eta + 2*E_f), sigma-margin required 5.7e-5; use 7.5e-5
// (same slack ratio as the harness-proven 1.5e-4 s-margin). sigma partials
// are O(1) (not O(128)), so fp32 rounding here is strictly tighter than R5.
#define MARGIN_HALF 7.5e-5f

// ---------------------------------------------------------------------------
// Architecture (R7):
//  * Filter math identical in exact arithmetic to proven R5/R6: bf16 hi/lo
//    MFMA terms (hh0,hh1,lh0,lh1,hl0,hl1), candidates within margin of the
//    row optimum re-evaluated with the bit-exact numpy replica.
//  * NEW sigma-scale: acc initialized to -c_sqr/2 (prep-computed csh), so
//    score sigma = acc directly; argMAX sigma == argmin s. Deletes the
//    per-score fmaf fixup entirely.
//  * NEW MBLK=128: each wave owns 32 rows (2 A-sets); every B-fragment
//    ds_read feeds 12 MFMAs (2 independent chains). Halves LDS reads,
//    staging, and barriers per row.
//  * Min+collect per 64-code half keeps live score regs at 32 ->
//    launch_bounds(256,4), LDS 39.9 KB -> 4 blocks/CU.
//  * x packed via v_cvt_pk_bf16_f32 (RNE, same bound as manual rne).
// ---------------------------------------------------------------------------

typedef __attribute__((ext_vector_type(8))) short s16x8;
typedef __attribute__((ext_vector_type(4))) float f32x4;
union U4S8 { uint4 u; s16x8 s; };

__device__ __forceinline__ unsigned short bf16_rne(float f) {
    unsigned u = __float_as_uint(f);
    return (unsigned short)((u + 0x7FFFu + ((u >> 16) & 1u)) >> 16);
}
__device__ __forceinline__ float bf16_tof(unsigned short h) {
    return __uint_as_float(((unsigned)h) << 16);
}
__device__ __forceinline__ unsigned cvtpk_bf16(float a, float b) {
    unsigned r;   // lo16 = bf16_rne(a), hi16 = bf16_rne(b)
    asm("v_cvt_pk_bf16_f32 %0, %1, %2" : "=v"(r) : "v"(a), "v"(b));
    return r;
}

// Async global->LDS (gfx950): LDS dest = wave-uniform base + lane*16.
__device__ __forceinline__ void g2lds16(const void* g, void* l) {
    __builtin_amdgcn_global_load_lds(
        (const __attribute__((address_space(1))) unsigned int*)g,
        (__attribute__((address_space(3))) unsigned int*)l,
        16, 0, 0);
}

// numpy pairwise_sum base case for n=64 (verified bit-exact in R2).
__device__ __forceinline__ float np_sumsq64(const float* v) {
    float r[8];
#pragma unroll
    for (int j = 0; j < 8; ++j) r[j] = __fmul_rn(v[j], v[j]);
#pragma unroll
    for (int i = 8; i < 64; i += 8) {
#pragma unroll
        for (int j = 0; j < 8; ++j)
            r[j] = __fadd_rn(r[j], __fmul_rn(v[i + j], v[i + j]));
    }
    float t01 = __fadd_rn(r[0], r[1]);
    float t23 = __fadd_rn(r[2], r[3]);
    float t45 = __fadd_rn(r[4], r[5]);
    float t67 = __fadd_rn(r[6], r[7]);
    return __fadd_rn(__fadd_rn(t01, t23), __fadd_rn(t45, t67));
}

// Streaming np_sumsq (identical op order; for the rare exact path).
__device__ __forceinline__ float np_xs_stream(const float4* __restrict__ xr) {
    float4 u = xr[0], w = xr[1];
    float r0 = __fmul_rn(u.x, u.x), r1 = __fmul_rn(u.y, u.y);
    float r2 = __fmul_rn(u.z, u.z), r3 = __fmul_rn(u.w, u.w);
    float r4 = __fmul_rn(w.x, w.x), r5 = __fmul_rn(w.y, w.y);
    float r6 = __fmul_rn(w.z, w.z), r7 = __fmul_rn(w.w, w.w);
#pragma unroll
    for (int i = 1; i < 8; ++i) {
        u = xr[2 * i]; w = xr[2 * i + 1];
        r0 = __fadd_rn(r0, __fmul_rn(u.x, u.x));
        r1 = __fadd_rn(r1, __fmul_rn(u.y, u.y));
        r2 = __fadd_rn(r2, __fmul_rn(u.z, u.z));
        r3 = __fadd_rn(r3, __fmul_rn(u.w, u.w));
        r4 = __fadd_rn(r4, __fmul_rn(w.x, w.x));
        r5 = __fadd_rn(r5, __fmul_rn(w.y, w.y));
        r6 = __fadd_rn(r6, __fmul_rn(w.z, w.z));
        r7 = __fadd_rn(r7, __fmul_rn(w.w, w.w));
    }
    float t01 = __fadd_rn(r0, r1), t23 = __fadd_rn(r2, r3);
    float t45 = __fadd_rn(r4, r5), t67 = __fadd_rn(r6, r7);
    return __fadd_rn(__fadd_rn(t01, t23), __fadd_rn(t45, t67));
}

// Sequential-FMA dot in ascending dim order (bit-exact vs reference mm).
__device__ __forceinline__ float dot_seq(const float4* __restrict__ xr,
                                         const float* __restrict__ c) {
    const float4* c4 = (const float4*)c;
    float a = 0.f;
#pragma unroll
    for (int i = 0; i < 16; ++i) {
        float4 xv = xr[i];
        float4 cv = c4[i];
        a = __fmaf_rn(xv.x, cv.x, a);
        a = __fmaf_rn(xv.y, cv.y, a);
        a = __fmaf_rn(xv.z, cv.z, a);
        a = __fmaf_rn(xv.w, cv.w, a);
    }
    return a;
}

__device__ __forceinline__ unsigned pair_pack(float va, float vb, int lo) {
    unsigned short ha = bf16_rne(va), hb = bf16_rne(vb);
    if (lo) {
        ha = bf16_rne(va - bf16_tof(ha));
        hb = bf16_rne(vb - bf16_tof(hb));
    }
    return (unsigned)ha | ((unsigned)hb << 16);
}

// Prep (combined, coalesced): blocks 0..31 pack FR granule-parallel
// (8192 threads, one uint4 store each); blocks 32..33 compute cs / csh.
// FR granule g = ((p*8+tt)*4 + fr)*64 + lane, lane = quad*16+mm,
// k = p*128+tt*16+mm, dims d = (fr&1)*32 + quad*8 + j, fr>>1 = lo-part.
__global__ void vq_prep(const float* __restrict__ cb, float* __restrict__ cs,
                        float* __restrict__ csh, unsigned short* __restrict__ FR) {
    int bid = blockIdx.x, t = threadIdx.x;
    if (bid < 32) {
        int g = bid * 256 + t;
        int lane = g & 63, fr = (g >> 6) & 3, tt = (g >> 8) & 7, p = g >> 11;
        int mm = lane & 15, quad = lane >> 4;
        int k = p * 128 + tt * 16 + mm;
        int d0 = (fr & 1) * 32 + quad * 8;
        int lo = fr >> 1;
        const float* src = cb + (size_t)k * DDIM + d0;
        float4 a = *(const float4*)src;
        float4 b = *(const float4*)(src + 4);
        uint4 pk;
        pk.x = pair_pack(a.x, a.y, lo);
        pk.y = pair_pack(a.z, a.w, lo);
        pk.z = pair_pack(b.x, b.y, lo);
        pk.w = pair_pack(b.z, b.w, lo);
        ((uint4*)FR)[g] = pk;
    } else {
        int k = (bid - 32) * 256 + t;
        if (k < KCODES) {
            float v[DDIM];
            const float4* c4 = (const float4*)(cb + (size_t)k * DDIM);
#pragma unroll
            for (int i = 0; i < DDIM / 4; ++i) {
                float4 tv = c4[i];
                v[4 * i + 0] = tv.x; v[4 * i + 1] = tv.y;
                v[4 * i + 2] = tv.z; v[4 * i + 3] = tv.w;
            }
            float s = np_sumsq64(v);
            cs[k] = s;
            csh[k] = -0.5f * s;        // exact (*0.5 is exact)
        }
    }
}

// x hi/lo pack via v_cvt_pk (RNE; residual subtraction plain fp32).
__device__ __forceinline__ void pack8(float4 a, float4 b, uint4& hi, uint4& lo) {
    hi.x = cvtpk_bf16(a.x, a.y);
    hi.y = cvtpk_bf16(a.z, a.w);
    hi.z = cvtpk_bf16(b.x, b.y);
    hi.w = cvtpk_bf16(b.z, b.w);
    float r0 = a.x - __uint_as_float(hi.x << 16);
    float r1 = a.y - __uint_as_float(hi.x & 0xffff0000u);
    float r2 = a.z - __uint_as_float(hi.y << 16);
    float r3 = a.w - __uint_as_float(hi.y & 0xffff0000u);
    float r4 = b.x - __uint_as_float(hi.z << 16);
    float r5 = b.y - __uint_as_float(hi.z & 0xffff0000u);
    float r6 = b.z - __uint_as_float(hi.w << 16);
    float r7 = b.w - __uint_as_float(hi.w & 0xffff0000u);
    lo.x = cvtpk_bf16(r0, r1);
    lo.y = cvtpk_bf16(r2, r3);
    lo.z = cvtpk_bf16(r4, r5);
    lo.w = cvtpk_bf16(r6, r7);
}

// Dynamic-LDS layout (bytes):
//   SB    @     0  (32768)  one quarter-pass of FR (2048 x 16B granules)
//   cnt   @ 32768  (  512)
//   lstk  @ 33280  ( 3072)  [128][6] candidate k
//   lsts  @ 36352  ( 3072)  [128][6] candidate sigma
//   win   @ 39424  (  512)
#define SMEM_BYTES 39936

#define MFMA16(A, B, C) __builtin_amdgcn_mfma_f32_16x16x32_bf16((A).s, (B).s, (C), 0, 0, 0)

__launch_bounds__(256, 4)
__global__ void vq_main(const float* __restrict__ x, const float* __restrict__ cb,
                        const float* __restrict__ cs, const float* __restrict__ csh,
                        const unsigned short* __restrict__ FR,
                        float* __restrict__ out) {
    extern __shared__ char smem[];
    uint4* SB   = (uint4*)(smem);
    int*   cnt  = (int*)  (smem + 32768);
    int*   lstk = (int*)  (smem + 33280);
    float* lsts = (float*)(smem + 36352);
    int*   win  = (int*)  (smem + 39424);

    const int t    = threadIdx.x;
    const int ln   = t & 63;
    const int wv   = t >> 6;
    const int m    = ln & 15;
    const int quad = ln >> 4;
    const int rowBlk0 = blockIdx.x * MBLK;

    // Issue stage for quarter-pass 0 immediately (overlaps x load + pack).
    {
        const char* gsrc = (const char*)FR;
#pragma unroll
        for (int i = 0; i < 8; ++i)
            g2lds16(gsrc + (size_t)(i * 256 + wv * 64 + ln) * 16,
                    (char*)SB + (size_t)(i * 256 + wv * 64) * 16);
    }
    if (t < 128) cnt[t] = 0;

    // A fragments, two row sets: rows wv*16+m (A) and 64+wv*16+m (B).
    const float* xrow0 = x + (size_t)(rowBlk0 + wv * 16 + m) * DDIM + quad * 8;
    const float* xrow1 = xrow0 + (size_t)64 * DDIM;
    U4S8 ah0A, ah1A, al0A, al1A, ah0B, ah1B, al0B, al1B;
    {
        float4 a0 = *(const float4*)(xrow0);
        float4 b0 = *(const float4*)(xrow0 + 4);
        float4 a1 = *(const float4*)(xrow0 + 32);
        float4 b1 = *(const float4*)(xrow0 + 36);
        pack8(a0, b0, ah0A.u, al0A.u);
        pack8(a1, b1, ah1A.u, al1A.u);
        a0 = *(const float4*)(xrow1);      b0 = *(const float4*)(xrow1 + 4);
        a1 = *(const float4*)(xrow1 + 32); b1 = *(const float4*)(xrow1 + 36);
        pack8(a0, b0, ah0B.u, al0B.u);
        pack8(a1, b1, ah1B.u, al1B.u);
    }

    float rm0[4] = {-INFINITY, -INFINITY, -INFINITY, -INFINITY};
    float rm1[4] = {-INFINITY, -INFINITY, -INFINITY, -INFINITY};

    for (int p = 0; p < 4; ++p) {
        __syncthreads();                   // stage p complete, lists coherent

        float chv[8];
#pragma unroll
        for (int tt = 0; tt < 8; ++tt) chv[tt] = csh[p * 128 + tt * 16 + m];

        f32x4 sA[4], sB[4];

        // ---------------- half 0: tt = 0..3 ----------------
#pragma unroll
        for (int q = 0; q < 4; ++q) {
            const int tt = q;
            U4S8 bh0, bh1, bl0, bl1;
            bh0.u = SB[(tt * 4 + 0) * 64 + ln];
            bh1.u = SB[(tt * 4 + 1) * 64 + ln];
            bl0.u = SB[(tt * 4 + 2) * 64 + ln];
            bl1.u = SB[(tt * 4 + 3) * 64 + ln];
            float ch = chv[tt];
            f32x4 a0 = {ch, ch, ch, ch}, a1 = {ch, ch, ch, ch};
            __builtin_amdgcn_s_setprio(1);
            a0 = MFMA16(ah0A, bh0, a0); a1 = MFMA16(ah0B, bh0, a1);
            a0 = MFMA16(ah1A, bh1, a0); a1 = MFMA16(ah1B, bh1, a1);
            a0 = MFMA16(al0A, bh0, a0); a1 = MFMA16(al0B, bh0, a1);
            a0 = MFMA16(al1A, bh1, a0); a1 = MFMA16(al1B, bh1, a1);
            a0 = MFMA16(ah0A, bl0, a0); a1 = MFMA16(ah0B, bl0, a1);
            a0 = MFMA16(ah1A, bl1, a0); a1 = MFMA16(ah1B, bl1, a1);
            __builtin_amdgcn_s_setprio(0);
            sA[q] = a0; sB[q] = a1;
        }
        // min/collect half 0 (frees sA/sB for half 1)
        {
            const int kbase = p * 128;
#pragma unroll
            for (int r = 0; r < 4; ++r) {
                float mx = fmaxf(fmaxf(sA[0][r], sA[1][r]), fmaxf(sA[2][r], sA[3][r]));
                mx = fmaxf(mx, __shfl_xor(mx, 1));
                mx = fmaxf(mx, __shfl_xor(mx, 2));
                mx = fmaxf(mx, __shfl_xor(mx, 4));
                mx = fmaxf(mx, __shfl_xor(mx, 8));
                rm0[r] = fmaxf(rm0[r], mx);
                float my = fmaxf(fmaxf(sB[0][r], sB[1][r]), fmaxf(sB[2][r], sB[3][r]));
                my = fmaxf(my, __shfl_xor(my, 1));
                my = fmaxf(my, __shfl_xor(my, 2));
                my = fmaxf(my, __shfl_xor(my, 4));
                my = fmaxf(my, __shfl_xor(my, 8));
                rm1[r] = fmaxf(rm1[r], my);
            }
#pragma unroll
            for (int r = 0; r < 4; ++r) {
                int lrow0 = wv * 16 + quad * 4 + r;
                float th0 = rm0[r] - MARGIN_HALF;
                float th1 = rm1[r] - MARGIN_HALF;
#pragma unroll
                for (int q = 0; q < 4; ++q) {
                    if (sA[q][r] >= th0) {
                        int pos = atomicAdd(&cnt[lrow0], 1);
                        if (pos < CAP) {
                            lstk[lrow0 * CAP + pos] = kbase + q * 16 + m;
                            lsts[lrow0 * CAP + pos] = sA[q][r];
                        }
                    }
                    if (sB[q][r] >= th1) {
                        int pos = atomicAdd(&cnt[lrow0 + 64], 1);
                        if (pos < CAP) {
                            lstk[(lrow0 + 64) * CAP + pos] = kbase + q * 16 + m;
                            lsts[(lrow0 + 64) * CAP + pos] = sB[q][r];
                        }
                    }
                }
            }
        }

        // ---------------- half 1: tt = 4..7 ----------------
#pragma unroll
        for (int q = 0; q < 4; ++q) {
            const int tt = 4 + q;
            U4S8 bh0, bh1, bl0, bl1;
            bh0.u = SB[(tt * 4 + 0) * 64 + ln];
            bh1.u = SB[(tt * 4 + 1) * 64 + ln];
            bl0.u = SB[(tt * 4 + 2) * 64 + ln];
            bl1.u = SB[(tt * 4 + 3) * 64 + ln];
            float ch = chv[tt];
            f32x4 a0 = {ch, ch, ch, ch}, a1 = {ch, ch, ch, ch};
            __builtin_amdgcn_s_setprio(1);
            a0 = MFMA16(ah0A, bh0, a0); a1 = MFMA16(ah0B, bh0, a1);
            a0 = MFMA16(ah1A, bh1, a0); a1 = MFMA16(ah1B, bh1, a1);
            a0 = MFMA16(al0A, bh0, a0); a1 = MFMA16(al0B, bh0, a1);
            a0 = MFMA16(al1A, bh1, a0); a1 = MFMA16(al1B, bh1, a1);
            a0 = MFMA16(ah0A, bl0, a0); a1 = MFMA16(ah0B, bl0, a1);
            a0 = MFMA16(ah1A, bl1, a0); a1 = MFMA16(ah1B, bl1, a1);
            __builtin_amdgcn_s_setprio(0);
            sA[q] = a0; sB[q] = a1;
        }

        __syncthreads();                   // all waves done reading SB

        if (p < 3) {                       // prefetch next quarter-pass
            const char* gsrc = (const char*)FR + (size_t)(p + 1) * 32768;
#pragma unroll
            for (int i = 0; i < 8; ++i)
                g2lds16(gsrc + (size_t)(i * 256 + wv * 64 + ln) * 16,
                        (char*)SB + (size_t)(i * 256 + wv * 64) * 16);
        }

        // min/collect half 1 (overlaps prefetch flight)
        {
            const int kbase = p * 128 + 64;
#pragma unroll
            for (int r = 0; r < 4; ++r) {
                float mx = fmaxf(fmaxf(sA[0][r], sA[1][r]), fmaxf(sA[2][r], sA[3][r]));
                mx = fmaxf(mx, __shfl_xor(mx, 1));
                mx = fmaxf(mx, __shfl_xor(mx, 2));
                mx = fmaxf(mx, __shfl_xor(mx, 4));
                mx = fmaxf(mx, __shfl_xor(mx, 8));
                rm0[r] = fmaxf(rm0[r], mx);
                float my = fmaxf(fmaxf(sB[0][r], sB[1][r]), fmaxf(sB[2][r], sB[3][r]));
                my = fmaxf(my, __shfl_xor(my, 1));
                my = fmaxf(my, __shfl_xor(my, 2));
                my = fmaxf(my, __shfl_xor(my, 4));
                my = fmaxf(my, __shfl_xor(my, 8));
                rm1[r] = fmaxf(rm1[r], my);
            }
#pragma unroll
            for (int r = 0; r < 4; ++r) {
                int lrow0 = wv * 16 + quad * 4 + r;
                float th0 = rm0[r] - MARGIN_HALF;
                float th1 = rm1[r] - MARGIN_HALF;
#pragma unroll
                for (int q = 0; q < 4; ++q) {
                    if (sA[q][r] >= th0) {
                        int pos = atomicAdd(&cnt[lrow0], 1);
                        if (pos < CAP) {
                            lstk[lrow0 * CAP + pos] = kbase + q * 16 + m;
                            lsts[lrow0 * CAP + pos] = sA[q][r];
                        }
                    }
                    if (sB[q][r] >= th1) {
                        int pos = atomicAdd(&cnt[lrow0 + 64], 1);
                        if (pos < CAP) {
                            lstk[(lrow0 + 64) * CAP + pos] = kbase + q * 16 + m;
                            lsts[(lrow0 + 64) * CAP + pos] = sB[q][r];
                        }
                    }
                }
            }
        }
    }

    __syncthreads();   // lists fully visible before final selection

    // Final selection: lanes m<8 per 16-group own rows (set, quad*4 + m&3).
    if (m < 8) {
        int r = m & 3;
        int set1 = m >> 2;
        int lrow = set1 * 64 + wv * 16 + quad * 4 + r;
        float v0 = set1 ? rm1[0] : rm0[0];
        float v1 = set1 ? rm1[1] : rm0[1];
        float v2 = set1 ? rm1[2] : rm0[2];
        float v3 = set1 ? rm1[3] : rm0[3];
        float rmf = (r == 0) ? v0 : (r == 1) ? v1 : (r == 2) ? v2 : v3;
        float thr = rmf - MARGIN_HALF;
        int c = cnt[lrow];
        int kb;
        const float4* xr = (const float4*)(x + (size_t)(rowBlk0 + lrow) * DDIM);
        if (c <= CAP) {
            int nc = 0, k1 = 0;
            for (int i = 0; i < c; ++i)
                if (lsts[lrow * CAP + i] >= thr) { ++nc; k1 = lstk[lrow * CAP + i]; }
            if (nc == 1) {
                kb = k1;
            } else {
                // Bit-exact numpy replica over surviving candidates (unsorted
                // insertion order; tie -> lowest k = numpy first occurrence).
                float xs = np_xs_stream(xr);
                float db = INFINITY; kb = 0x7fffffff;
                for (int i = 0; i < c; ++i) {
                    if (lsts[lrow * CAP + i] >= thr) {
                        int k = lstk[lrow * CAP + i];
                        float a = dot_seq(xr, cb + (size_t)k * DDIM);
                        float d = __fadd_rn(__fadd_rn(xs, cs[k]), __fmul_rn(-2.0f, a));
                        if (d < db || (d == db && k < kb)) { db = d; kb = k; }
                    }
                }
            }
        } else {
            // Overflow: exact scan of all 512 (ascending + strict '<').
            float xs = np_xs_stream(xr);
            float db = INFINITY; kb = 0;
            for (int k = 0; k < KCODES; ++k) {
                float a = dot_seq(xr, cb + (size_t)k * DDIM);
                float d = __fadd_rn(__fadd_rn(xs, cs[k]), __fmul_rn(-2.0f, a));
                if (d < db) { db = d; kb = k; }
            }
        }
        win[lrow] = kb;
        out[2 * ND + (size_t)(rowBlk0 + lrow)] = (float)kb;
    }
    __syncthreads();

    // Epilogue: z_q = z_q_bar = codebook[win], fully coalesced block writes.
#pragma unroll
    for (int i = 0; i < 8; ++i) {
        int g   = t + i * 256;                // 0..2047 float4-granules
        int row = g >> 4, cc = g & 15;
        int kb  = win[row];
        float4 v = *(const float4*)(cb + (size_t)kb * DDIM + cc * 4);
        size_t gr = (size_t)(rowBlk0 + row) * DDIM + (size_t)cc * 4;
        *(float4*)(out + gr) = v;
        *(float4*)(out + ND + gr) = v;
    }
}

extern "C" void kernel_launch(void* const* d_in, const int* in_sizes, int n_in,
                              void* d_out, int out_size, void* d_ws, size_t ws_size,
                              hipStream_t stream) {
    const float* z  = (const float*)d_in[0];   // [N, D] fp32
    const float* cb = (const float*)d_in[1];   // [K, D] fp32
    float* out = (float*)d_out;                // [N*D | N*D | N] fp32
    float* cs          = (float*)d_ws;                          // 512 f32 exact
    float* csh         = (float*)((char*)d_ws + 2048);          // 512 f32 (-cs/2)
    unsigned short* FR = (unsigned short*)((char*)d_ws + 4096); // 128 KB frag-ordered

    (void)hipFuncSetAttribute((const void*)vq_main,
                              hipFuncAttributeMaxDynamicSharedMemorySize,
                              SMEM_BYTES);
    vq_prep<<<34, 256, 0, stream>>>(cb, cs, csh, FR);
    vq_main<<<NROWS / MBLK, 256, SMEM_BYTES, stream>>>(z, cb, cs, csh, FR, out);
}

// Round 3
// 236.352 us; speedup vs baseline: 2.3499x; 2.3499x over previous
//
#include <hip/hip_runtime.h>
#include <math.h>

// Problem constants (fixed by the reference).
#define KCODES 512
#define DDIM   64
#define NROWS  262144
#define ND     ((size_t)NROWS * DDIM)
#define MBLK   64            // rows per block (R6-proven structure)
#define CAP    8             // candidate-list capacity per row
// sigma-scale margin: sigma = dot - c^2/2 = -s_filter/2. R5's proven s-margin
// 1.5e-4 (required 1.14e-4) maps to sigma-margin 7.5e-5 (required 5.7e-5).
// Sigma partials are O(0.2) so fp32 accumulation error is strictly tighter
// than the R5 bound. Proven on-HW in R7 (absmax = 0).
#define MARGIN_HALF 7.5e-5f

// ---------------------------------------------------------------------------
// Architecture (R8) = R6 main loop (harness-proven 113 us, 64 VGPR, no spill)
//  + R7's proven low-pressure deltas:
//  * coalesced granule-parallel prep (was ~130 us at 2 blocks, now ~5 us)
//  * sigma-scale: acc init -c^2/2, score = raw MFMA acc, argMAX
//    (deletes the per-score fmaf fixup)
//  * v_cvt_pk_bf16_f32 x-packing (halves prologue VALU)
// R7 post-mortem: doubling live state (2 row-sets) at the allocator's 64-reg
// operating point spilled ~88 B/thread to scratch (+45 MB WRITE_SIZE, 4.4x
// slower). R8 keeps live state at R6 levels: 16 A-frag regs + 32 score regs.
// ---------------------------------------------------------------------------

typedef __attribute__((ext_vector_type(8))) short s16x8;
typedef __attribute__((ext_vector_type(4))) float f32x4;
union U4S8 { uint4 u; s16x8 s; };

__device__ __forceinline__ unsigned short bf16_rne(float f) {
    unsigned u = __float_as_uint(f);
    return (unsigned short)((u + 0x7FFFu + ((u >> 16) & 1u)) >> 16);
}
__device__ __forceinline__ float bf16_tof(unsigned short h) {
    return __uint_as_float(((unsigned)h) << 16);
}
__device__ __forceinline__ unsigned cvtpk_bf16(float a, float b) {
    unsigned r;   // lo16 = bf16_rne(a), hi16 = bf16_rne(b)
    asm("v_cvt_pk_bf16_f32 %0, %1, %2" : "=v"(r) : "v"(a), "v"(b));
    return r;
}

// Async global->LDS (gfx950): LDS dest = wave-uniform base + lane*16.
__device__ __forceinline__ void g2lds16(const void* g, void* l) {
    __builtin_amdgcn_global_load_lds(
        (const __attribute__((address_space(1))) unsigned int*)g,
        (__attribute__((address_space(3))) unsigned int*)l,
        16, 0, 0);
}

// numpy pairwise_sum base case for n=64 (verified bit-exact in R2).
__device__ __forceinline__ float np_sumsq64(const float* v) {
    float r[8];
#pragma unroll
    for (int j = 0; j < 8; ++j) r[j] = __fmul_rn(v[j], v[j]);
#pragma unroll
    for (int i = 8; i < 64; i += 8) {
#pragma unroll
        for (int j = 0; j < 8; ++j)
            r[j] = __fadd_rn(r[j], __fmul_rn(v[i + j], v[i + j]));
    }
    float t01 = __fadd_rn(r[0], r[1]);
    float t23 = __fadd_rn(r[2], r[3]);
    float t45 = __fadd_rn(r[4], r[5]);
    float t67 = __fadd_rn(r[6], r[7]);
    return __fadd_rn(__fadd_rn(t01, t23), __fadd_rn(t45, t67));
}

// Streaming np_sumsq (identical op order; for the rare exact path).
__device__ __forceinline__ float np_xs_stream(const float4* __restrict__ xr) {
    float4 u = xr[0], w = xr[1];
    float r0 = __fmul_rn(u.x, u.x), r1 = __fmul_rn(u.y, u.y);
    float r2 = __fmul_rn(u.z, u.z), r3 = __fmul_rn(u.w, u.w);
    float r4 = __fmul_rn(w.x, w.x), r5 = __fmul_rn(w.y, w.y);
    float r6 = __fmul_rn(w.z, w.z), r7 = __fmul_rn(w.w, w.w);
#pragma unroll
    for (int i = 1; i < 8; ++i) {
        u = xr[2 * i]; w = xr[2 * i + 1];
        r0 = __fadd_rn(r0, __fmul_rn(u.x, u.x));
        r1 = __fadd_rn(r1, __fmul_rn(u.y, u.y));
        r2 = __fadd_rn(r2, __fmul_rn(u.z, u.z));
        r3 = __fadd_rn(r3, __fmul_rn(u.w, u.w));
        r4 = __fadd_rn(r4, __fmul_rn(w.x, w.x));
        r5 = __fadd_rn(r5, __fmul_rn(w.y, w.y));
        r6 = __fadd_rn(r6, __fmul_rn(w.z, w.z));
        r7 = __fadd_rn(r7, __fmul_rn(w.w, w.w));
    }
    float t01 = __fadd_rn(r0, r1), t23 = __fadd_rn(r2, r3);
    float t45 = __fadd_rn(r4, r5), t67 = __fadd_rn(r6, r7);
    return __fadd_rn(__fadd_rn(t01, t23), __fadd_rn(t45, t67));
}

// Sequential-FMA dot in ascending dim order (bit-exact vs reference mm).
__device__ __forceinline__ float dot_seq(const float4* __restrict__ xr,
                                         const float* __restrict__ c) {
    const float4* c4 = (const float4*)c;
    float a = 0.f;
#pragma unroll
    for (int i = 0; i < 16; ++i) {
        float4 xv = xr[i];
        float4 cv = c4[i];
        a = __fmaf_rn(xv.x, cv.x, a);
        a = __fmaf_rn(xv.y, cv.y, a);
        a = __fmaf_rn(xv.z, cv.z, a);
        a = __fmaf_rn(xv.w, cv.w, a);
    }
    return a;
}

__device__ __forceinline__ unsigned pair_pack(float va, float vb, int lo) {
    unsigned short ha = bf16_rne(va), hb = bf16_rne(vb);
    if (lo) {
        ha = bf16_rne(va - bf16_tof(ha));
        hb = bf16_rne(vb - bf16_tof(hb));
    }
    return (unsigned)ha | ((unsigned)hb << 16);
}

// Prep (combined, coalesced — R7-proven): blocks 0..31 pack FR
// granule-parallel (8192 threads, one uint4 store each); blocks 32..33
// compute cs (numpy-exact) and csh = -cs/2 (exact scaling).
// FR granule g = ((p*8+tt)*4 + fr)*64 + lane, lane = quad*16+mm,
// k = p*128+tt*16+mm, dims d = (fr&1)*32 + quad*8 + j, fr>>1 = lo-part.
__global__ void vq_prep(const float* __restrict__ cb, float* __restrict__ cs,
                        float* __restrict__ csh, unsigned short* __restrict__ FR) {
    int bid = blockIdx.x, t = threadIdx.x;
    if (bid < 32) {
        int g = bid * 256 + t;
        int lane = g & 63, fr = (g >> 6) & 3, tt = (g >> 8) & 7, p = g >> 11;
        int mm = lane & 15, quad = lane >> 4;
        int k = p * 128 + tt * 16 + mm;
        int d0 = (fr & 1) * 32 + quad * 8;
        int lo = fr >> 1;
        const float* src = cb + (size_t)k * DDIM + d0;
        float4 a = *(const float4*)src;
        float4 b = *(const float4*)(src + 4);
        uint4 pk;
        pk.x = pair_pack(a.x, a.y, lo);
        pk.y = pair_pack(a.z, a.w, lo);
        pk.z = pair_pack(b.x, b.y, lo);
        pk.w = pair_pack(b.z, b.w, lo);
        ((uint4*)FR)[g] = pk;
    } else {
        int k = (bid - 32) * 256 + t;
        if (k < KCODES) {
            float v[DDIM];
            const float4* c4 = (const float4*)(cb + (size_t)k * DDIM);
#pragma unroll
            for (int i = 0; i < DDIM / 4; ++i) {
                float4 tv = c4[i];
                v[4 * i + 0] = tv.x; v[4 * i + 1] = tv.y;
                v[4 * i + 2] = tv.z; v[4 * i + 3] = tv.w;
            }
            float s = np_sumsq64(v);
            cs[k] = s;
            csh[k] = -0.5f * s;        // exact
        }
    }
}

// x hi/lo pack via v_cvt_pk (RNE; residual subtraction exact in fp32 for
// the hi-part magnitudes involved; proven on-HW in R7).
__device__ __forceinline__ void pack8(float4 a, float4 b, uint4& hi, uint4& lo) {
    hi.x = cvtpk_bf16(a.x, a.y);
    hi.y = cvtpk_bf16(a.z, a.w);
    hi.z = cvtpk_bf16(b.x, b.y);
    hi.w = cvtpk_bf16(b.z, b.w);
    float r0 = a.x - __uint_as_float(hi.x << 16);
    float r1 = a.y - __uint_as_float(hi.x & 0xffff0000u);
    float r2 = a.z - __uint_as_float(hi.y << 16);
    float r3 = a.w - __uint_as_float(hi.y & 0xffff0000u);
    float r4 = b.x - __uint_as_float(hi.z << 16);
    float r5 = b.y - __uint_as_float(hi.z & 0xffff0000u);
    float r6 = b.z - __uint_as_float(hi.w << 16);
    float r7 = b.w - __uint_as_float(hi.w & 0xffff0000u);
    lo.x = cvtpk_bf16(r0, r1);
    lo.y = cvtpk_bf16(r2, r3);
    lo.z = cvtpk_bf16(r4, r5);
    lo.w = cvtpk_bf16(r6, r7);
}

// Dynamic-LDS layout (bytes) — identical to R6:
//   SB    @     0  (32768)  one quarter-pass of FR (2048 x 16B granules)
//   cnt   @ 32768  (  256)
//   lstk  @ 33024  ( 2048)  [64][8] candidate k
//   lsts  @ 35072  ( 2048)  [64][8] candidate sigma
//   win   @ 37120  (  256)
#define SMEM_BYTES 37376

__launch_bounds__(256, 4)
__global__ void vq_main(const float* __restrict__ x, const float* __restrict__ cb,
                        const float* __restrict__ cs, const float* __restrict__ csh,
                        const unsigned short* __restrict__ FR,
                        float* __restrict__ out) {
    extern __shared__ char smem[];
    uint4* SB   = (uint4*)(smem);
    int*   cnt  = (int*)  (smem + 32768);
    int*   lstk = (int*)  (smem + 33024);
    float* lsts = (float*)(smem + 35072);
    int*   win  = (int*)  (smem + 37120);

    const int t    = threadIdx.x;
    const int ln   = t & 63;
    const int wv   = t >> 6;
    const int m    = ln & 15;
    const int quad = ln >> 4;
    const int rowBlk0 = blockIdx.x * MBLK;

    // Issue stage for quarter-pass 0 immediately (overlaps x load + pack).
    {
        const char* gsrc = (const char*)FR;
#pragma unroll
        for (int i = 0; i < 8; ++i)
            g2lds16(gsrc + (size_t)(i * 256 + wv * 64 + ln) * 16,
                    (char*)SB + (size_t)(i * 256 + wv * 64) * 16);
    }

    if (t < 64) cnt[t] = 0;

    // A fragments: rows wv*16+m, dims quad*8.. (chunk0) / 32+quad*8.. (chunk1)
    const float* xrow = x + (size_t)(rowBlk0 + wv * 16 + m) * DDIM + quad * 8;
    U4S8 axh0, axh1, axl0, axl1;
    {
        float4 a0 = *(const float4*)(xrow);
        float4 b0 = *(const float4*)(xrow + 4);
        float4 a1 = *(const float4*)(xrow + 32);
        float4 b1 = *(const float4*)(xrow + 36);
        pack8(a0, b0, axh0.u, axl0.u);
        pack8(a1, b1, axh1.u, axl1.u);
    }

    float rm[4] = {-INFINITY, -INFINITY, -INFINITY, -INFINITY};

    for (int p = 0; p < 4; ++p) {
        __syncthreads();                       // stage p complete (drains vmcnt)

        float chv[8];
#pragma unroll
        for (int tt = 0; tt < 8; ++tt) chv[tt] = csh[p * 128 + tt * 16 + m];

        float s[4][8];
#pragma unroll
        for (int tt = 0; tt < 8; ++tt) {
            U4S8 bh0, bh1, bl0, bl1;
            bh0.u = SB[(tt * 4 + 0) * 64 + ln];
            bh1.u = SB[(tt * 4 + 1) * 64 + ln];
            bl0.u = SB[(tt * 4 + 2) * 64 + ln];
            bl1.u = SB[(tt * 4 + 3) * 64 + ln];
            float ch = chv[tt];
            f32x4 acc = {ch, ch, ch, ch};      // sigma-scale: C-in = -c^2/2
            acc = __builtin_amdgcn_mfma_f32_16x16x32_bf16(axh0.s, bh0.s, acc, 0, 0, 0);
            acc = __builtin_amdgcn_mfma_f32_16x16x32_bf16(axh1.s, bh1.s, acc, 0, 0, 0);
            acc = __builtin_amdgcn_mfma_f32_16x16x32_bf16(axl0.s, bh0.s, acc, 0, 0, 0);
            acc = __builtin_amdgcn_mfma_f32_16x16x32_bf16(axl1.s, bh1.s, acc, 0, 0, 0);
            acc = __builtin_amdgcn_mfma_f32_16x16x32_bf16(axh0.s, bl0.s, acc, 0, 0, 0);
            acc = __builtin_amdgcn_mfma_f32_16x16x32_bf16(axh1.s, bl1.s, acc, 0, 0, 0);
#pragma unroll
            for (int r = 0; r < 4; ++r)
                s[r][tt] = acc[r];             // sigma score, argMAX
        }

        __syncthreads();                       // all waves done reading SB

        if (p < 3) {                           // prefetch next quarter-pass
            const char* gsrc = (const char*)FR + (size_t)(p + 1) * 32768;
#pragma unroll
            for (int i = 0; i < 8; ++i)
                g2lds16(gsrc + (size_t)(i * 256 + wv * 64 + ln) * 16,
                        (char*)SB + (size_t)(i * 256 + wv * 64) * 16);
        }

        // Row-max: in-lane tree + 4-step butterfly over the 16-lane group.
#pragma unroll
        for (int r = 0; r < 4; ++r) {
            float mx = s[r][0];
#pragma unroll
            for (int tt = 1; tt < 8; ++tt) mx = fmaxf(mx, s[r][tt]);
            mx = fmaxf(mx, __shfl_xor(mx, 1, 64));
            mx = fmaxf(mx, __shfl_xor(mx, 2, 64));
            mx = fmaxf(mx, __shfl_xor(mx, 4, 64));
            mx = fmaxf(mx, __shfl_xor(mx, 8, 64));
            rm[r] = fmaxf(rm[r], mx);
        }
        // Collect candidates within running-max - MARGIN (superset of
        // final-max - MARGIN since rm only increases -> thr only tightens;
        // the argmax itself is always collected in its own pass).
#pragma unroll
        for (int r = 0; r < 4; ++r) {
            float thr = rm[r] - MARGIN_HALF;
            int lrow = wv * 16 + quad * 4 + r;
#pragma unroll
            for (int tt = 0; tt < 8; ++tt) {
                if (s[r][tt] >= thr) {
                    int pos = atomicAdd(&cnt[lrow], 1);
                    if (pos < CAP) {
                        lstk[lrow * CAP + pos] = p * 128 + tt * 16 + m;
                        lsts[lrow * CAP + pos] = s[r][tt];
                    }
                }
            }
        }
    }

    __syncthreads();   // lists fully visible before final selection

    // Final selection: lane m<4 of each group owns row wv*16+quad*4+m.
    if (m < 4) {
        int lrow = wv * 16 + quad * 4 + m;
        float rmf = (m == 0) ? rm[0] : (m == 1) ? rm[1] : (m == 2) ? rm[2] : rm[3];
        float thr = rmf - MARGIN_HALF;
        int c = cnt[lrow];
        int kb;
        const float4* xr = (const float4*)(x + (size_t)(rowBlk0 + lrow) * DDIM);
        if (c <= CAP) {
            int nc = 0, k1 = 0;
            for (int i = 0; i < c; ++i)
                if (lsts[lrow * CAP + i] >= thr) { ++nc; k1 = lstk[lrow * CAP + i]; }
            if (nc == 1) {
                kb = k1;
            } else {
                // Bit-exact numpy replica over surviving candidates
                // (tie -> lowest k = numpy first occurrence).
                float xs = np_xs_stream(xr);
                float db = INFINITY; kb = 0x7fffffff;
                for (int i = 0; i < c; ++i) {
                    if (lsts[lrow * CAP + i] >= thr) {
                        int k = lstk[lrow * CAP + i];
                        float a = dot_seq(xr, cb + (size_t)k * DDIM);
                        float d = __fadd_rn(__fadd_rn(xs, cs[k]), __fmul_rn(-2.0f, a));
                        if (d < db || (d == db && k < kb)) { db = d; kb = k; }
                    }
                }
            }
        } else {
            // Overflow: exact scan of all 512 (ascending + strict '<').
            float xs = np_xs_stream(xr);
            float db = INFINITY; kb = 0;
            for (int k = 0; k < KCODES; ++k) {
                float a = dot_seq(xr, cb + (size_t)k * DDIM);
                float d = __fadd_rn(__fadd_rn(xs, cs[k]), __fmul_rn(-2.0f, a));
                if (d < db) { db = d; kb = k; }
            }
        }
        win[lrow] = kb;
        out[2 * ND + (size_t)(rowBlk0 + lrow)] = (float)kb;
    }
    __syncthreads();

    // Epilogue: z_q = z_q_bar = codebook[win], fully coalesced block writes.
#pragma unroll
    for (int i = 0; i < 4; ++i) {
        int g   = t + i * 256;                // 0..1023 float4-granules
        int row = g >> 4, cc = g & 15;
        int kb  = win[row];
        float4 v = *(const float4*)(cb + (size_t)kb * DDIM + cc * 4);
        size_t gr = (size_t)(rowBlk0 + row) * DDIM + (size_t)cc * 4;
        *(float4*)(out + gr) = v;
        *(float4*)(out + ND + gr) = v;
    }
}

extern "C" void kernel_launch(void* const* d_in, const int* in_sizes, int n_in,
                              void* d_out, int out_size, void* d_ws, size_t ws_size,
                              hipStream_t stream) {
    const float* z  = (const float*)d_in[0];   // [N, D] fp32
    const float* cb = (const float*)d_in[1];   // [K, D] fp32
    float* out = (float*)d_out;                // [N*D | N*D | N] fp32
    float* cs          = (float*)d_ws;                          // 512 f32 exact
    float* csh         = (float*)((char*)d_ws + 2048);          // 512 f32 (-cs/2)
    unsigned short* FR = (unsigned short*)((char*)d_ws + 4096); // 128 KB frag-ordered

    (void)hipFuncSetAttribute((const void*)vq_main,
                              hipFuncAttributeMaxDynamicSharedMemorySize,
                              SMEM_BYTES);
    vq_prep<<<34, 256, 0, stream>>>(cb, cs, csh, FR);
    vq_main<<<NROWS / MBLK, 256, SMEM_BYTES, stream>>>(z, cb, cs, csh, FR, out);
}